// Round 1
// baseline (485.726 us; speedup 1.0000x reference)
//
#include <hip/hip_runtime.h>
#include <hip/hip_bf16.h>
#include <stdint.h>

typedef __bf16 bf16_8 __attribute__((ext_vector_type(8)));
typedef float f32_4 __attribute__((ext_vector_type(4)));

static __device__ __forceinline__ unsigned short f2bf(float f) {
    union { float f; unsigned int u; } v; v.f = f;
    unsigned int u = v.u;
    unsigned int r = (u + 0x7fffu + ((u >> 16) & 1u)) >> 16;
    return (unsigned short)r;
}

// ---------------- fp32 -> bf16 elementwise convert ----------------
__global__ void cvt_bf16_kernel(const float* __restrict__ in,
                                unsigned short* __restrict__ out, int n4) {
    int i = blockIdx.x * blockDim.x + threadIdx.x;
    if (i < n4) {
        float4 f = ((const float4*)in)[i];
        ushort4 o;
        o.x = f2bf(f.x); o.y = f2bf(f.y); o.z = f2bf(f.z); o.w = f2bf(f.w);
        ((ushort4*)out)[i] = o;
    }
}

// ---------------- transpose + convert: in [K][N] fp32 -> out [N][K] bf16 ----
__global__ void transpose_cvt_kernel(const float* __restrict__ in,
                                     unsigned short* __restrict__ out,
                                     int K, int N) {
    __shared__ unsigned short tile[64][65];
    int k0 = blockIdx.y * 64, n0 = blockIdx.x * 64;
    int tc = threadIdx.x & 63, tr = threadIdx.x >> 6;  // tr: 0..3
    for (int p = 0; p < 16; ++p) {
        int k = p * 4 + tr;
        tile[k][tc] = f2bf(in[(size_t)(k0 + k) * N + n0 + tc]);
    }
    __syncthreads();
    for (int p = 0; p < 16; ++p) {
        int n = p * 4 + tr;
        out[(size_t)(n0 + n) * K + k0 + tc] = tile[tc][n];
    }
}

// ---------------- bf16 MFMA GEMM: C = A[M][K] @ Bt[N][K]^T + bias ----------
// mode 0: scatter to Q/K/V bf16 buffers [B*H][T][64], Q scaled by 0.125
// mode 1: fp32 output [M][N]
#define BM 128
#define BN 128
#define BK 32
#define LDA 40  // padded LDS row stride (elements); 80 B = multiple of 16 B

__global__ __launch_bounds__(256) void gemm_bf16(
    const unsigned short* __restrict__ A,
    const unsigned short* __restrict__ Bt,
    const float* __restrict__ bias,
    int M, int N, int K, int mode,
    unsigned short* __restrict__ q_out, unsigned short* __restrict__ k_out,
    unsigned short* __restrict__ v_out, float* __restrict__ outf) {
    __shared__ __align__(16) unsigned short As[BM * LDA];
    __shared__ __align__(16) unsigned short Bs[BN * LDA];
    int tid = threadIdx.x;
    int wave = tid >> 6, lane = tid & 63;
    int wm = wave & 1, wn = wave >> 1;
    int quad = lane >> 4, l16 = lane & 15;
    int m0 = blockIdx.y * BM, n0 = blockIdx.x * BN;

    f32_4 acc[4][4] = {};

    int srow = tid >> 2;         // 0..63
    int scol = (tid & 3) * 8;    // 0,8,16,24

    for (int kt = 0; kt < K; kt += BK) {
        for (int p = 0; p < 2; ++p) {
            int r = srow + p * 64;
            bf16_8 av = *(const bf16_8*)(A + (size_t)(m0 + r) * K + kt + scol);
            *(bf16_8*)(As + r * LDA + scol) = av;
            bf16_8 bv = *(const bf16_8*)(Bt + (size_t)(n0 + r) * K + kt + scol);
            *(bf16_8*)(Bs + r * LDA + scol) = bv;
        }
        __syncthreads();
        bf16_8 af[4], bfr[4];
        for (int i = 0; i < 4; ++i)
            af[i] = *(const bf16_8*)(As + (wm * 64 + i * 16 + l16) * LDA + quad * 8);
        for (int j = 0; j < 4; ++j)
            bfr[j] = *(const bf16_8*)(Bs + (wn * 64 + j * 16 + l16) * LDA + quad * 8);
        for (int i = 0; i < 4; ++i)
            for (int j = 0; j < 4; ++j)
                acc[i][j] = __builtin_amdgcn_mfma_f32_16x16x32_bf16(
                    af[i], bfr[j], acc[i][j], 0, 0, 0);
        __syncthreads();
    }

    if (mode == 0) {
        // rows m0..m0+127 all within one batch (2048 % 128 == 0)
        int b = m0 >> 11;
        int tbase = (m0 & 2047) + wm * 64;
        for (int j = 0; j < 4; ++j) {
            int n = n0 + wn * 64 + j * 16 + l16;
            int which = n >> 10, c = n & 1023, h = c >> 6, d = c & 63;
            float bs = bias[n];
            unsigned short* dst = which == 0 ? q_out : (which == 1 ? k_out : v_out);
            float scale = which == 0 ? 0.125f : 1.0f;
            size_t base = ((size_t)(b * 16 + h) * 2048) * 64 + d;
            for (int i = 0; i < 4; ++i) {
                int t0 = tbase + i * 16 + quad * 4;
                for (int r = 0; r < 4; ++r) {
                    float val = (acc[i][j][r] + bs) * scale;
                    dst[base + (size_t)(t0 + r) * 64] = f2bf(val);
                }
            }
        }
    } else {
        for (int j = 0; j < 4; ++j) {
            int n = n0 + wn * 64 + j * 16 + l16;
            float bs = bias[n];
            for (int i = 0; i < 4; ++i) {
                int m = m0 + wm * 64 + i * 16 + quad * 4;
                for (int r = 0; r < 4; ++r)
                    outf[(size_t)(m + r) * N + n] = acc[i][j][r] + bs;
            }
        }
    }
}

// ---------------- flash-style causal attention ------------------------------
// Q/K/V: [B*H][T][64] bf16, Q pre-scaled by 1/8. Y: [B*T][1024] bf16.
#define KSTR 72  // LDS row stride; 144 B = multiple of 16 B

__global__ __launch_bounds__(256) void attn_kernel(
    const unsigned short* __restrict__ Q, const unsigned short* __restrict__ Kb,
    const unsigned short* __restrict__ Vb, unsigned short* __restrict__ Y,
    int T) {
    __shared__ __align__(16) unsigned short Ks[64 * KSTR];
    __shared__ __align__(16) unsigned short Vts[64 * KSTR];
    __shared__ __align__(16) unsigned short Ps[4 * 32 * KSTR];

    int tid = threadIdx.x;
    int wave = tid >> 6, lane = tid & 63;
    int quad = lane >> 4, l16 = lane & 15;
    int qt = gridDim.x - 1 - blockIdx.x;  // heavy tiles first
    int bh = blockIdx.y;
    int b = bh >> 4, h = bh & 15;
    int q0 = qt * 128;
    int qw = q0 + wave * 32;  // this wave's 32 q rows

    // Q fragments (A-operand layout), resident in registers
    bf16_8 qa[2][2];
    for (int rf = 0; rf < 2; ++rf)
        for (int ks = 0; ks < 2; ++ks)
            qa[rf][ks] = *(const bf16_8*)(Q + ((size_t)bh * T + qw + rf * 16 + l16) * 64 +
                                          ks * 32 + quad * 8);

    f32_4 o[2][4] = {};
    float mrow[2][4], lrow[2][4];
    for (int rf = 0; rf < 2; ++rf)
        for (int r = 0; r < 4; ++r) { mrow[rf][r] = -1e30f; lrow[rf][r] = 0.0f; }

    unsigned short* Pw = Ps + wave * 32 * KSTR;
    int nkt = 2 * qt + 2;

    for (int ktile = 0; ktile < nkt; ++ktile) {
        int kb = ktile * 64;
        // stage K tile [64][64] and V^T tile [64(d)][64(tk)]
        {
            int r = tid >> 3;            // 0..31
            int c8 = (tid & 7) * 8;      // 0..56
            for (int p = 0; p < 2; ++p) {
                int rr = r + p * 32;
                size_t goff = ((size_t)bh * T + kb + rr) * 64 + c8;
                bf16_8 kv = *(const bf16_8*)(Kb + goff);
                *(bf16_8*)(Ks + rr * KSTR + c8) = kv;
                uint4 vv = *(const uint4*)(Vb + goff);
                Vts[(c8 + 0) * KSTR + rr] = (unsigned short)(vv.x);
                Vts[(c8 + 1) * KSTR + rr] = (unsigned short)(vv.x >> 16);
                Vts[(c8 + 2) * KSTR + rr] = (unsigned short)(vv.y);
                Vts[(c8 + 3) * KSTR + rr] = (unsigned short)(vv.y >> 16);
                Vts[(c8 + 4) * KSTR + rr] = (unsigned short)(vv.z);
                Vts[(c8 + 5) * KSTR + rr] = (unsigned short)(vv.z >> 16);
                Vts[(c8 + 6) * KSTR + rr] = (unsigned short)(vv.w);
                Vts[(c8 + 7) * KSTR + rr] = (unsigned short)(vv.w >> 16);
            }
        }
        __syncthreads();

        // S = Q @ K^T  (C layout: row = quad*4+reg, col = l16, per 16x16 frag)
        bf16_8 kf[4][2];
        for (int jf = 0; jf < 4; ++jf)
            for (int ks = 0; ks < 2; ++ks)
                kf[jf][ks] = *(const bf16_8*)(Ks + (jf * 16 + l16) * KSTR + ks * 32 + quad * 8);
        f32_4 s[2][4] = {};
        for (int rf = 0; rf < 2; ++rf)
            for (int jf = 0; jf < 4; ++jf) {
                s[rf][jf] = __builtin_amdgcn_mfma_f32_16x16x32_bf16(qa[rf][0], kf[jf][0], s[rf][jf], 0, 0, 0);
                s[rf][jf] = __builtin_amdgcn_mfma_f32_16x16x32_bf16(qa[rf][1], kf[jf][1], s[rf][jf], 0, 0, 0);
            }

        // causal mask on the (at most) two diagonal tiles
        if (ktile >= nkt - 2) {
            for (int rf = 0; rf < 2; ++rf)
                for (int jf = 0; jf < 4; ++jf)
                    for (int r = 0; r < 4; ++r) {
                        int qrow = qw + rf * 16 + quad * 4 + r;
                        int col = kb + jf * 16 + l16;
                        if (col > qrow) s[rf][jf][r] = -1e30f;
                    }
        }

        // online softmax + write P to wave-private LDS
        for (int rf = 0; rf < 2; ++rf) {
            for (int r = 0; r < 4; ++r) {
                float mx = s[rf][0][r];
                mx = fmaxf(mx, s[rf][1][r]);
                mx = fmaxf(mx, s[rf][2][r]);
                mx = fmaxf(mx, s[rf][3][r]);
                for (int off = 1; off < 16; off <<= 1) mx = fmaxf(mx, __shfl_xor(mx, off));
                float mnew = fmaxf(mrow[rf][r], mx);
                float alpha = __expf(mrow[rf][r] - mnew);
                mrow[rf][r] = mnew;
                float rsum = 0.0f;
                for (int jf = 0; jf < 4; ++jf) {
                    float p = __expf(s[rf][jf][r] - mnew);
                    s[rf][jf][r] = p;
                    rsum += p;
                }
                for (int off = 1; off < 16; off <<= 1) rsum += __shfl_xor(rsum, off);
                lrow[rf][r] = lrow[rf][r] * alpha + rsum;
                for (int df = 0; df < 4; ++df) o[rf][df][r] *= alpha;
            }
        }
        for (int rf = 0; rf < 2; ++rf)
            for (int jf = 0; jf < 4; ++jf)
                for (int r = 0; r < 4; ++r)
                    Pw[(rf * 16 + quad * 4 + r) * KSTR + jf * 16 + l16] = f2bf(s[rf][jf][r]);

        // O += P @ V  (P as A-operand from LDS, V^T as B-operand)
        for (int ks = 0; ks < 2; ++ks) {
            bf16_8 pa[2];
            for (int rf = 0; rf < 2; ++rf)
                pa[rf] = *(const bf16_8*)(Pw + (rf * 16 + l16) * KSTR + ks * 32 + quad * 8);
            for (int df = 0; df < 4; ++df) {
                bf16_8 vf = *(const bf16_8*)(Vts + (df * 16 + l16) * KSTR + ks * 32 + quad * 8);
                for (int rf = 0; rf < 2; ++rf)
                    o[rf][df] = __builtin_amdgcn_mfma_f32_16x16x32_bf16(pa[rf], vf, o[rf][df], 0, 0, 0);
            }
        }
        __syncthreads();
    }

    // epilogue: normalize and write Y[b*T + t][h*64 + d]
    for (int rf = 0; rf < 2; ++rf)
        for (int df = 0; df < 4; ++df)
            for (int r = 0; r < 4; ++r) {
                int trow = qw + rf * 16 + quad * 4 + r;
                float val = o[rf][df][r] / lrow[rf][r];
                Y[((size_t)b * T + trow) * 1024 + h * 64 + df * 16 + l16] = f2bf(val);
            }
}

extern "C" void kernel_launch(void* const* d_in, const int* in_sizes, int n_in,
                              void* d_out, int out_size, void* d_ws, size_t ws_size,
                              hipStream_t stream) {
    const float* x = (const float*)d_in[0];
    const float* w_qkv = (const float*)d_in[1];
    const float* b_qkv = (const float*)d_in[2];
    const float* w_proj = (const float*)d_in[3];
    const float* b_proj = (const float*)d_in[4];
    float* out = (float*)d_out;

    // workspace carve (ushort elements)
    unsigned short* xbf = (unsigned short*)d_ws;        // 8192*1024
    unsigned short* wqkvt = xbf + 8388608;              // 3072*1024
    unsigned short* wprojt = wqkvt + 3145728;           // 1024*1024
    unsigned short* Qb = wprojt + 1048576;              // 64*2048*64
    unsigned short* Kb = Qb + 8388608;
    unsigned short* Vb = Kb + 8388608;
    unsigned short* Yb = Vb + 8388608;

    hipLaunchKernelGGL(cvt_bf16_kernel, dim3(8192), dim3(256), 0, stream,
                       x, xbf, 2097152);
    hipLaunchKernelGGL(transpose_cvt_kernel, dim3(48, 16), dim3(256), 0, stream,
                       w_qkv, wqkvt, 1024, 3072);
    hipLaunchKernelGGL(transpose_cvt_kernel, dim3(16, 16), dim3(256), 0, stream,
                       w_proj, wprojt, 1024, 1024);
    hipLaunchKernelGGL(gemm_bf16, dim3(24, 64), dim3(256), 0, stream,
                       xbf, wqkvt, b_qkv, 8192, 3072, 1024, 0,
                       Qb, Kb, Vb, (float*)nullptr);
    hipLaunchKernelGGL(attn_kernel, dim3(16, 64), dim3(256), 0, stream,
                       Qb, Kb, Vb, Yb, 2048);
    hipLaunchKernelGGL(gemm_bf16, dim3(8, 64), dim3(256), 0, stream,
                       Yb, wprojt, b_proj, 8192, 1024, 1024, 1,
                       (unsigned short*)nullptr, (unsigned short*)nullptr,
                       (unsigned short*)nullptr, out);
}

// Round 2
// 359.324 us; speedup vs baseline: 1.3518x; 1.3518x over previous
//
#include <hip/hip_runtime.h>
#include <hip/hip_bf16.h>
#include <stdint.h>

typedef __bf16 bf16_8 __attribute__((ext_vector_type(8)));
typedef float f32_4 __attribute__((ext_vector_type(4)));

static __device__ __forceinline__ unsigned short f2bf(float f) {
    union { float f; unsigned int u; } v; v.f = f;
    unsigned int u = v.u;
    unsigned int r = (u + 0x7fffu + ((u >> 16) & 1u)) >> 16;
    return (unsigned short)r;
}

// ---------------- fp32 -> bf16 elementwise convert ----------------
__global__ void cvt_bf16_kernel(const float* __restrict__ in,
                                unsigned short* __restrict__ out, int n4) {
    int i = blockIdx.x * blockDim.x + threadIdx.x;
    if (i < n4) {
        float4 f = ((const float4*)in)[i];
        ushort4 o;
        o.x = f2bf(f.x); o.y = f2bf(f.y); o.z = f2bf(f.z); o.w = f2bf(f.w);
        ((ushort4*)out)[i] = o;
    }
}

// ---------------- transpose + convert: in [K][N] fp32 -> out [N][K] bf16 ----
__global__ void transpose_cvt_kernel(const float* __restrict__ in,
                                     unsigned short* __restrict__ out,
                                     int K, int N) {
    __shared__ unsigned short tile[64][65];
    int k0 = blockIdx.y * 64, n0 = blockIdx.x * 64;
    int tc = threadIdx.x & 63, tr = threadIdx.x >> 6;  // tr: 0..3
    for (int p = 0; p < 16; ++p) {
        int k = p * 4 + tr;
        tile[k][tc] = f2bf(in[(size_t)(k0 + k) * N + n0 + tc]);
    }
    __syncthreads();
    for (int p = 0; p < 16; ++p) {
        int n = p * 4 + tr;
        out[(size_t)(n0 + n) * K + k0 + tc] = tile[tc][n];
    }
}

// ---------------- bf16 MFMA GEMM: C = A[M][K] @ Bt[N][K]^T + bias ----------
// mode 0: scatter to Q/K bf16 buffers [B*H][T][64] (Q scaled 0.125) and
//         V TRANSPOSED: Vt[B*H][64][T]
// mode 1: fp32 output [M][N]
#define BM 128
#define BN 128
#define BK 32
#define LDA 40  // padded LDS row stride (elements); 80 B

__global__ __launch_bounds__(256) void gemm_bf16(
    const unsigned short* __restrict__ A,
    const unsigned short* __restrict__ Bt,
    const float* __restrict__ bias,
    int M, int N, int K, int mode,
    unsigned short* __restrict__ q_out, unsigned short* __restrict__ k_out,
    unsigned short* __restrict__ v_out, float* __restrict__ outf) {
    __shared__ __align__(16) unsigned short As[BM * LDA];
    __shared__ __align__(16) unsigned short Bs[BN * LDA];
    int tid = threadIdx.x;
    int wave = tid >> 6, lane = tid & 63;
    int wm = wave & 1, wn = wave >> 1;
    int quad = lane >> 4, l16 = lane & 15;
    int m0 = blockIdx.y * BM, n0 = blockIdx.x * BN;

    f32_4 acc[4][4] = {};

    int srow = tid >> 2;         // 0..63
    int scol = (tid & 3) * 8;    // 0,8,16,24

    for (int kt = 0; kt < K; kt += BK) {
        for (int p = 0; p < 2; ++p) {
            int r = srow + p * 64;
            bf16_8 av = *(const bf16_8*)(A + (size_t)(m0 + r) * K + kt + scol);
            *(bf16_8*)(As + r * LDA + scol) = av;
            bf16_8 bv = *(const bf16_8*)(Bt + (size_t)(n0 + r) * K + kt + scol);
            *(bf16_8*)(Bs + r * LDA + scol) = bv;
        }
        __syncthreads();
        bf16_8 af[4], bfr[4];
        for (int i = 0; i < 4; ++i)
            af[i] = *(const bf16_8*)(As + (wm * 64 + i * 16 + l16) * LDA + quad * 8);
        for (int j = 0; j < 4; ++j)
            bfr[j] = *(const bf16_8*)(Bs + (wn * 64 + j * 16 + l16) * LDA + quad * 8);
        for (int i = 0; i < 4; ++i)
            for (int j = 0; j < 4; ++j)
                acc[i][j] = __builtin_amdgcn_mfma_f32_16x16x32_bf16(
                    af[i], bfr[j], acc[i][j], 0, 0, 0);
        __syncthreads();
    }

    if (mode == 0) {
        // rows m0..m0+127 all within one batch (2048 % 128 == 0)
        int b = m0 >> 11;
        int tbase = (m0 & 2047) + wm * 64;
        // `which` is uniform across j and lanes (64-aligned window)
        int nw0 = n0 + wn * 64;
        int which = nw0 >> 10;
        for (int j = 0; j < 4; ++j) {
            int n = nw0 + j * 16 + l16;
            int c = n & 1023, h = c >> 6, d = c & 63;
            float bs = bias[n];
            int bh = (b << 4) + h;
            if (which == 2) {
                // V transposed: Vt[bh][d][t]
                size_t base = ((size_t)bh * 64 + d) * 2048;
                for (int i = 0; i < 4; ++i) {
                    int t0 = tbase + i * 16 + quad * 4;
                    ushort4 pk;
                    pk.x = f2bf(acc[i][j][0] + bs);
                    pk.y = f2bf(acc[i][j][1] + bs);
                    pk.z = f2bf(acc[i][j][2] + bs);
                    pk.w = f2bf(acc[i][j][3] + bs);
                    *(ushort4*)(v_out + base + t0) = pk;
                }
            } else {
                unsigned short* dst = which == 0 ? q_out : k_out;
                float scale = which == 0 ? 0.125f : 1.0f;
                size_t base = ((size_t)bh * 2048) * 64 + d;
                for (int i = 0; i < 4; ++i) {
                    int t0 = tbase + i * 16 + quad * 4;
                    for (int r = 0; r < 4; ++r) {
                        float val = (acc[i][j][r] + bs) * scale;
                        dst[base + (size_t)(t0 + r) * 64] = f2bf(val);
                    }
                }
            }
        }
    } else {
        for (int j = 0; j < 4; ++j) {
            int n = n0 + wn * 64 + j * 16 + l16;
            float bs = bias[n];
            for (int i = 0; i < 4; ++i) {
                int m = m0 + wm * 64 + i * 16 + quad * 4;
                for (int r = 0; r < 4; ++r)
                    outf[(size_t)(m + r) * N + n] = acc[i][j][r] + bs;
            }
        }
    }
}

// ---------------- flash-style causal attention, transposed-S variant -------
// Q/K: [B*H][T][64] bf16 (Q pre-scaled by 1/8). Vt: [B*H][64][T] bf16.
// Y: [B*T][1024] bf16.
// Block: 4 waves, 128 q rows (32 per wave). S^T = K@Q^T so that softmax is
// per-lane-column and P^T packs as b64 LDS writes; PV as O^T = V^T @ P^T with
// all-vector LDS reads.
#define KSTR 72   // 64 + 8 pad, 144 B rows
#define PSTR 40   // 32 + 8 pad, 80 B rows

__global__ __launch_bounds__(256) void attn_kernel(
    const unsigned short* __restrict__ Q, const unsigned short* __restrict__ Kb,
    const unsigned short* __restrict__ Vt, unsigned short* __restrict__ Y,
    int T) {
    __shared__ __align__(16) unsigned short SMEM[64 * KSTR * 2 + 4 * 32 * PSTR];
    unsigned short* Ks = SMEM;
    unsigned short* Vts = SMEM + 64 * KSTR;

    int tid = threadIdx.x;
    int wave = tid >> 6, lane = tid & 63;
    int quad = lane >> 4, l16 = lane & 15;
    int qt = gridDim.x - 1 - blockIdx.x;  // heavy tiles first
    int bh = blockIdx.y;
    int b = bh >> 4, h = bh & 15;
    int q0 = qt * 128;
    int qw = q0 + wave * 32;  // this wave's 32 q rows

    unsigned short* Pt = SMEM + 128 * KSTR + wave * 32 * PSTR;

    // Q fragments: lane&15 = q (also valid as MFMA B-operand), quad*8 = d
    bf16_8 qa[2][2];
    for (int qf = 0; qf < 2; ++qf)
        for (int ks = 0; ks < 2; ++ks)
            qa[qf][ks] = *(const bf16_8*)(Q + ((size_t)bh * T + qw + qf * 16 + l16) * 64 +
                                          ks * 32 + quad * 8);

    f32_4 o[4][2] = {};          // [df][qf]: d = df*16+quad*4+r, q = qf*16+l16
    float mrow[2] = {-1e30f, -1e30f};
    float lrow[2] = {0.0f, 0.0f};

    int srow = tid >> 2;          // 0..63
    int schunk = (tid & 3) * 16;  // 0,16,32,48
    int nkt = 2 * qt + 2;

    for (int ktile = 0; ktile < nkt; ++ktile) {
        int kb = ktile * 64;
        // stage K tile [t][d] and V^T tile [d][tk] — all vector ops
        {
            const unsigned short* kg = Kb + ((size_t)bh * T + kb + srow) * 64 + schunk;
            uint4 ka0 = *(const uint4*)kg;
            uint4 ka1 = *(const uint4*)(kg + 8);
            const unsigned short* vg = Vt + ((size_t)bh * 64 + srow) * T + kb + schunk;
            uint4 va0 = *(const uint4*)vg;
            uint4 va1 = *(const uint4*)(vg + 8);
            *(uint4*)(Ks + srow * KSTR + schunk) = ka0;
            *(uint4*)(Ks + srow * KSTR + schunk + 8) = ka1;
            *(uint4*)(Vts + srow * KSTR + schunk) = va0;
            *(uint4*)(Vts + srow * KSTR + schunk + 8) = va1;
        }
        __syncthreads();

        if (kb <= qw + 31) {  // wave has unmasked work in this k tile
            // S^T = K @ Q^T : lane holds (k = kf*16+quad*4+r, q = qf*16+l16)
            f32_4 s[4][2] = {};
            for (int kf = 0; kf < 4; ++kf) {
                bf16_8 ka0 = *(const bf16_8*)(Ks + (kf * 16 + l16) * KSTR + quad * 8);
                bf16_8 ka1 = *(const bf16_8*)(Ks + (kf * 16 + l16) * KSTR + 32 + quad * 8);
                for (int qf = 0; qf < 2; ++qf) {
                    s[kf][qf] = __builtin_amdgcn_mfma_f32_16x16x32_bf16(ka0, qa[qf][0], s[kf][qf], 0, 0, 0);
                    s[kf][qf] = __builtin_amdgcn_mfma_f32_16x16x32_bf16(ka1, qa[qf][1], s[kf][qf], 0, 0, 0);
                }
            }

            // causal mask
            if (kb + 63 > qw) {
                for (int kf = 0; kf < 4; ++kf)
                    for (int qf = 0; qf < 2; ++qf) {
                        int q = qw + qf * 16 + l16;
                        int kk = kb + kf * 16 + quad * 4;
                        for (int r = 0; r < 4; ++r)
                            if (kk + r > q) s[kf][qf][r] = -1e30f;
                    }
            }

            // online softmax: per lane, one q per qf; reduce across quads
            for (int qf = 0; qf < 2; ++qf) {
                float mx = s[0][qf][0];
                for (int kf = 0; kf < 4; ++kf)
                    for (int r = 0; r < 4; ++r) mx = fmaxf(mx, s[kf][qf][r]);
                mx = fmaxf(mx, __shfl_xor(mx, 16));
                mx = fmaxf(mx, __shfl_xor(mx, 32));
                float mnew = fmaxf(mrow[qf], mx);
                float alpha = __expf(mrow[qf] - mnew);
                mrow[qf] = mnew;
                float rsum = 0.0f;
                for (int kf = 0; kf < 4; ++kf)
                    for (int r = 0; r < 4; ++r) {
                        float p = __expf(s[kf][qf][r] - mnew);
                        s[kf][qf][r] = p;
                        rsum += p;
                    }
                rsum += __shfl_xor(rsum, 16);
                rsum += __shfl_xor(rsum, 32);
                lrow[qf] = lrow[qf] * alpha + rsum;
                for (int df = 0; df < 4; ++df)
                    for (int r = 0; r < 4; ++r) o[df][qf][r] *= alpha;
            }

            // PV in two 32-k halves: write P^T (b64 packed), O^T += V^T @ P^T
            for (int half = 0; half < 2; ++half) {
                for (int kfh = 0; kfh < 2; ++kfh) {
                    int kf = half * 2 + kfh;
                    for (int qf = 0; qf < 2; ++qf) {
                        ushort4 pk;
                        pk.x = f2bf(s[kf][qf][0]);
                        pk.y = f2bf(s[kf][qf][1]);
                        pk.z = f2bf(s[kf][qf][2]);
                        pk.w = f2bf(s[kf][qf][3]);
                        *(ushort4*)(Pt + (qf * 16 + l16) * PSTR + kfh * 16 + quad * 4) = pk;
                    }
                }
                bf16_8 pb[2];
                for (int qf = 0; qf < 2; ++qf)
                    pb[qf] = *(const bf16_8*)(Pt + (qf * 16 + l16) * PSTR + quad * 8);
                for (int df = 0; df < 4; ++df) {
                    bf16_8 va = *(const bf16_8*)(Vts + (df * 16 + l16) * KSTR + half * 32 + quad * 8);
                    for (int qf = 0; qf < 2; ++qf)
                        o[df][qf] = __builtin_amdgcn_mfma_f32_16x16x32_bf16(va, pb[qf], o[df][qf], 0, 0, 0);
                }
            }
        }
        __syncthreads();
    }

    // epilogue: normalize, transpose O^T -> O via LDS (reuse Ks/Vts region),
    // then coalesced Y writes
    unsigned short* Ot = SMEM;  // 128 rows x KSTR
    for (int qf = 0; qf < 2; ++qf) {
        float inv = 1.0f / lrow[qf];
        int row = wave * 32 + qf * 16 + l16;
        for (int df = 0; df < 4; ++df) {
            ushort4 pk;
            pk.x = f2bf(o[df][qf][0] * inv);
            pk.y = f2bf(o[df][qf][1] * inv);
            pk.z = f2bf(o[df][qf][2] * inv);
            pk.w = f2bf(o[df][qf][3] * inv);
            *(ushort4*)(Ot + row * KSTR + df * 16 + quad * 4) = pk;
        }
    }
    __syncthreads();
    {
        int row = tid >> 1;            // 0..127
        int cc = (tid & 1) * 32;       // 0,32
        unsigned short* dst = Y + ((size_t)b * T + q0 + row) * 1024 + h * 64 + cc;
        const unsigned short* src = Ot + row * KSTR + cc;
        uint4 o0 = *(const uint4*)(src);
        uint4 o1 = *(const uint4*)(src + 8);
        uint4 o2 = *(const uint4*)(src + 16);
        uint4 o3 = *(const uint4*)(src + 24);
        *(uint4*)(dst) = o0;
        *(uint4*)(dst + 8) = o1;
        *(uint4*)(dst + 16) = o2;
        *(uint4*)(dst + 24) = o3;
    }
}

extern "C" void kernel_launch(void* const* d_in, const int* in_sizes, int n_in,
                              void* d_out, int out_size, void* d_ws, size_t ws_size,
                              hipStream_t stream) {
    const float* x = (const float*)d_in[0];
    const float* w_qkv = (const float*)d_in[1];
    const float* b_qkv = (const float*)d_in[2];
    const float* w_proj = (const float*)d_in[3];
    const float* b_proj = (const float*)d_in[4];
    float* out = (float*)d_out;

    // workspace carve (ushort elements)
    unsigned short* xbf = (unsigned short*)d_ws;        // 8192*1024
    unsigned short* wqkvt = xbf + 8388608;              // 3072*1024
    unsigned short* wprojt = wqkvt + 3145728;           // 1024*1024
    unsigned short* Qb = wprojt + 1048576;              // 64*2048*64
    unsigned short* Kb = Qb + 8388608;
    unsigned short* Vtb = Kb + 8388608;                 // transposed V
    unsigned short* Yb = Vtb + 8388608;

    hipLaunchKernelGGL(cvt_bf16_kernel, dim3(8192), dim3(256), 0, stream,
                       x, xbf, 2097152);
    hipLaunchKernelGGL(transpose_cvt_kernel, dim3(48, 16), dim3(256), 0, stream,
                       w_qkv, wqkvt, 1024, 3072);
    hipLaunchKernelGGL(transpose_cvt_kernel, dim3(16, 16), dim3(256), 0, stream,
                       w_proj, wprojt, 1024, 1024);
    hipLaunchKernelGGL(gemm_bf16, dim3(24, 64), dim3(256), 0, stream,
                       xbf, wqkvt, b_qkv, 8192, 3072, 1024, 0,
                       Qb, Kb, Vtb, (float*)nullptr);
    hipLaunchKernelGGL(attn_kernel, dim3(16, 64), dim3(256), 0, stream,
                       Qb, Kb, Vtb, Yb, 2048);
    hipLaunchKernelGGL(gemm_bf16, dim3(8, 64), dim3(256), 0, stream,
                       Yb, wprojt, b_proj, 8192, 1024, 1024, 1,
                       (unsigned short*)nullptr, (unsigned short*)nullptr,
                       (unsigned short*)nullptr, out);
}